// Round 1
// baseline (447.637 us; speedup 1.0000x reference)
//
#include <hip/hip_runtime.h>
#include <math.h>

#define BB 1024
#define CC 50000
#define DD 256
#define LRATE 0.5f

// ------------------------------------------------------------------
// K1: zero the class-count array (ws is poisoned 0xAA each call)
__global__ void k_zero_counts(int* __restrict__ counts) {
    int i = blockIdx.x * blockDim.x + threadIdx.x;
    if (i < CC) counts[i] = 0;
}

// ------------------------------------------------------------------
// K2: scan each one-hot row of y -> label index; atomic class counts.
// One block per row, float4 coalesced reads (12500 float4 per row).
__global__ void k_labels(const float* __restrict__ y,
                         int* __restrict__ labels,
                         int* __restrict__ counts) {
    int b = blockIdx.x;
    const float4* row = (const float4*)(y + (size_t)b * CC);
    int found = -1;
    for (int i = threadIdx.x; i < CC / 4; i += blockDim.x) {
        float4 v = row[i];
        if (v.x > 0.5f) found = 4 * i;
        else if (v.y > 0.5f) found = 4 * i + 1;
        else if (v.z > 0.5f) found = 4 * i + 2;
        else if (v.w > 0.5f) found = 4 * i + 3;
    }
    __shared__ int s_lab;
    if (threadIdx.x == 0) s_lab = 0;
    __syncthreads();
    if (found >= 0) s_lab = found;   // exactly one thread hits (one-hot)
    __syncthreads();
    if (threadIdx.x == 0) {
        labels[b] = s_lab;
        atomicAdd(&counts[s_lab], 1);
    }
}

// ------------------------------------------------------------------
// K3: inv_ns[c] = 1 / (count[c] + 1)
__global__ void k_inv(const int* __restrict__ counts, float* __restrict__ inv_ns) {
    int i = blockIdx.x * blockDim.x + threadIdx.x;
    if (i < CC) inv_ns[i] = 1.0f / ((float)counts[i] + 1.0f);
}

// ------------------------------------------------------------------
// K4a: copy center -> out_center (float4 grid-stride)
__global__ void k_copy_center(const float4* __restrict__ src, float4* __restrict__ dst) {
    const int n4 = CC * DD / 4;   // 3.2M
    int i = blockIdx.x * blockDim.x + threadIdx.x;
    if (i < n4) dst[i] = src[i];
}

// ------------------------------------------------------------------
// K4b: per-sample dist, loss norm, scatter-add LR*dist into out_center.
// One block (256 threads == DD) per row.
__global__ void k_update(const float* __restrict__ x,
                         const float* __restrict__ center,
                         const int* __restrict__ labels,
                         float* __restrict__ out_center,
                         float* __restrict__ loss_norm) {
    int b = blockIdx.x;
    int d = threadIdx.x;           // DD == blockDim.x == 256
    int lab = labels[b];
    float dist = x[(size_t)b * DD + d] - center[(size_t)lab * DD + d];
    atomicAdd(&out_center[(size_t)lab * DD + d], LRATE * dist);

    float sq = dist * dist;
    #pragma unroll
    for (int off = 32; off > 0; off >>= 1)
        sq += __shfl_down(sq, off, 64);
    __shared__ float s[4];
    int wave = threadIdx.x >> 6;
    if ((threadIdx.x & 63) == 0) s[wave] = sq;
    __syncthreads();
    if (threadIdx.x == 0)
        loss_norm[b] = sqrtf(s[0] + s[1] + s[2] + s[3]);
}

// ------------------------------------------------------------------
// K5: loss[b,c] = loss_norm[b] * inv_ns[c]. Write-dominated (204.8 MB).
// grid.x covers the 12500 float4 columns; grid.y tiles rows (16/block)
// so each block loads its inv_ns float4 once and reuses across rows.
#define ROWS_PER_BLK 16
__global__ void k_loss(const float* __restrict__ loss_norm,
                       const float* __restrict__ inv_ns,
                       float* __restrict__ out_loss) {
    const int C4 = CC / 4;   // 12500
    int c4 = blockIdx.x * blockDim.x + threadIdx.x;
    if (c4 >= C4) return;
    float4 inv = ((const float4*)inv_ns)[c4];
    int b0 = blockIdx.y * ROWS_PER_BLK;
    #pragma unroll
    for (int r = 0; r < ROWS_PER_BLK; ++r) {
        int b = b0 + r;
        float ln = loss_norm[b];
        float4 o;
        o.x = ln * inv.x; o.y = ln * inv.y; o.z = ln * inv.z; o.w = ln * inv.w;
        ((float4*)(out_loss + (size_t)b * CC))[c4] = o;
    }
}

// ------------------------------------------------------------------
extern "C" void kernel_launch(void* const* d_in, const int* in_sizes, int n_in,
                              void* d_out, int out_size, void* d_ws, size_t ws_size,
                              hipStream_t stream) {
    const float* x      = (const float*)d_in[0];   // [B, D]
    const float* y      = (const float*)d_in[1];   // [B, C] one-hot
    const float* center = (const float*)d_in[2];   // [C, D]

    float* out_loss   = (float*)d_out;                      // [B, C]
    float* out_center = (float*)d_out + (size_t)BB * CC;    // [C, D]

    // workspace layout (all 16B-aligned regions)
    char* ws = (char*)d_ws;
    int*   counts    = (int*)ws;                         // C ints
    float* inv_ns    = (float*)(ws + ((size_t)CC * 4 + 255) / 256 * 256);
    char*  ws2       = (char*)inv_ns + ((size_t)CC * 4 + 255) / 256 * 256;
    int*   labels    = (int*)ws2;                        // B ints
    float* loss_norm = (float*)(ws2 + 4096);             // B floats

    k_zero_counts<<<(CC + 255) / 256, 256, 0, stream>>>(counts);
    k_labels<<<BB, 256, 0, stream>>>(y, labels, counts);
    k_inv<<<(CC + 255) / 256, 256, 0, stream>>>(counts, inv_ns);
    k_copy_center<<<(CC * DD / 4 + 255) / 256, 256, 0, stream>>>(
        (const float4*)center, (float4*)out_center);
    k_update<<<BB, DD, 0, stream>>>(x, center, labels, out_center, loss_norm);

    dim3 lgrid((CC / 4 + 255) / 256, BB / ROWS_PER_BLK);
    k_loss<<<lgrid, 256, 0, stream>>>(loss_norm, inv_ns, out_loss);
}

// Round 3
// 420.026 us; speedup vs baseline: 1.0657x; 1.0657x over previous
//
#include <hip/hip_runtime.h>
#include <math.h>

#define BB 1024
#define CC 50000
#define DD 256
#define LRATE 0.5f

// ------------------------------------------------------------------
// K1: out_center = center (float4 copy) AND zero the class counts.
// 12500 blocks x 256 threads: 3.2M float4 copies; first 12500 threads
// also zero counts as int4 (50000 ints = 12500 int4).
__global__ void k_init(const float4* __restrict__ center,
                       float4* __restrict__ out_center,
                       int4* __restrict__ counts) {
    int i = blockIdx.x * blockDim.x + threadIdx.x;
    const int n4 = CC * DD / 4;         // 3,200,000
    if (i < n4) out_center[i] = center[i];
    if (i < CC / 4)                     // 12,500 int4  (was CC/16 — the R2 bug)
        counts[i] = make_int4(0, 0, 0, 0);
}

// ------------------------------------------------------------------
// K2: per-row one-hot scan (chunked early-exit) -> label; then
// dist = x - center[lab], atomic scatter LR*dist into out_center,
// block-reduce ||dist|| -> loss_norm[b]. One block (256 = DD) per row.
#define CHUNK_ITERS 8                   // 8*256 uint4 = 8192 cols/chunk
__global__ void k_labels_update(const unsigned int* __restrict__ y,
                                const float* __restrict__ x,
                                const float* __restrict__ center,
                                float* __restrict__ out_center,
                                int* __restrict__ counts,
                                float* __restrict__ loss_norm) {
    int b = blockIdx.x;
    const uint4* row = (const uint4*)(y + (size_t)b * CC);
    __shared__ int s_lab;
    __shared__ float s_part[4];
    if (threadIdx.x == 0) s_lab = -1;
    __syncthreads();

    const int C4 = CC / 4;              // 12500
    for (int base = 0; base < C4; base += 256 * CHUNK_ITERS) {
        #pragma unroll
        for (int j = 0; j < CHUNK_ITERS; ++j) {
            int i = base + j * 256 + threadIdx.x;
            if (i < C4) {
                uint4 v = row[i];       // 0.0f has all-zero bits; 1.0f doesn't
                if (v.x | v.y | v.z | v.w) {
                    // exactly one nonzero in the whole row -> single writer
                    s_lab = 4 * i + (v.x ? 0 : (v.y ? 1 : (v.z ? 2 : 3)));
                }
            }
        }
        __syncthreads();                // make chunk's write visible
        int found = s_lab;              // read in a no-write interval
        __syncthreads();                // all reads done before next chunk writes
        if (found >= 0) break;          // uniform across block
    }

    int lab = s_lab;                    // stable after loop
    if (lab < 0) lab = 0;               // safety (reference labels always valid)
    if (threadIdx.x == 0) atomicAdd(&counts[lab], 1);

    int d = threadIdx.x;                // DD == 256 == blockDim.x
    float dist = x[(size_t)b * DD + d] - center[(size_t)lab * DD + d];
    atomicAdd(&out_center[(size_t)lab * DD + d], LRATE * dist);

    float sq = dist * dist;
    #pragma unroll
    for (int off = 32; off > 0; off >>= 1)
        sq += __shfl_down(sq, off, 64);
    if ((threadIdx.x & 63) == 0) s_part[threadIdx.x >> 6] = sq;
    __syncthreads();
    if (threadIdx.x == 0)
        loss_norm[b] = sqrtf(s_part[0] + s_part[1] + s_part[2] + s_part[3]);
}

// ------------------------------------------------------------------
// K3: loss[b,c] = loss_norm[b] / (counts[c] + 1). Write-dominated
// (204.8 MB). inv computed inline from counts (int4) — no k_inv pass.
// grid.x tiles the 12500 float4 columns; grid.y tiles rows, 16/block.
#define ROWS_PER_BLK 16
__global__ void k_loss(const float* __restrict__ loss_norm,
                       const int* __restrict__ counts,
                       float* __restrict__ out_loss) {
    const int C4 = CC / 4;              // 12500
    int c4 = blockIdx.x * blockDim.x + threadIdx.x;
    if (c4 >= C4) return;
    int4 cnt = ((const int4*)counts)[c4];
    float4 inv;
    inv.x = 1.0f / ((float)cnt.x + 1.0f);
    inv.y = 1.0f / ((float)cnt.y + 1.0f);
    inv.z = 1.0f / ((float)cnt.z + 1.0f);
    inv.w = 1.0f / ((float)cnt.w + 1.0f);
    int b0 = blockIdx.y * ROWS_PER_BLK;
    #pragma unroll
    for (int r = 0; r < ROWS_PER_BLK; ++r) {
        int b = b0 + r;
        float ln = loss_norm[b];
        float4 o;
        o.x = ln * inv.x; o.y = ln * inv.y; o.z = ln * inv.z; o.w = ln * inv.w;
        ((float4*)(out_loss + (size_t)b * CC))[c4] = o;
    }
}

// ------------------------------------------------------------------
extern "C" void kernel_launch(void* const* d_in, const int* in_sizes, int n_in,
                              void* d_out, int out_size, void* d_ws, size_t ws_size,
                              hipStream_t stream) {
    const float* x      = (const float*)d_in[0];          // [B, D]
    const unsigned int* y = (const unsigned int*)d_in[1]; // [B, C] one-hot fp32 bits
    const float* center = (const float*)d_in[2];          // [C, D]

    float* out_loss   = (float*)d_out;                    // [B, C]
    float* out_center = (float*)d_out + (size_t)BB * CC;  // [C, D]

    // workspace: counts (50000 ints) @ 0, loss_norm (1024 floats) @ 256KB
    int*   counts    = (int*)d_ws;
    float* loss_norm = (float*)((char*)d_ws + 256 * 1024);

    k_init<<<CC * DD / 4 / 256, 256, 0, stream>>>(
        (const float4*)center, (float4*)out_center, (int4*)counts);

    k_labels_update<<<BB, DD, 0, stream>>>(
        y, x, center, out_center, counts, loss_norm);

    dim3 lgrid((CC / 4 + 255) / 256, BB / ROWS_PER_BLK);
    k_loss<<<lgrid, 256, 0, stream>>>(loss_norm, counts, out_loss);
}